// Round 19
// baseline (485.071 us; speedup 1.0000x reference)
//
#include <hip/hip_runtime.h>
#include <hip/hip_bf16.h>
#include <hip/hip_fp16.h>

#define N_NODES 50000
#define N_EDGES 1600000
#define ET (N_EDGES + N_NODES)
#define HID 128
#define N_LAYERS 4
#define EPS 1e-5f
#define NEG 0.2f
#define RB 256      // bn reduce blocks
#define NBUCK 196   // ceil(N_NODES/256), 256-node buckets
#define BCHUNK 8192
#define LOG2E 1.44269504088896f
#define AGG_BLOCKS 2048

typedef __attribute__((ext_vector_type(8))) short s16x8;
typedef __attribute__((ext_vector_type(8))) __bf16 bfx8;
typedef __attribute__((ext_vector_type(4))) float fx4;
typedef __attribute__((ext_vector_type(2))) _Float16 f16x2;

__device__ __forceinline__ unsigned int packbf2(float a, float b) {
    unsigned int ua = __float_as_uint(a);
    ua = (ua + 0x7fffu + ((ua >> 16) & 1u)) >> 16;
    unsigned int ub = __float_as_uint(b);
    ub = (ub + 0x7fffu + ((ub >> 16) & 1u)) & 0xffff0000u;
    return (ua & 0xffffu) | ub;
}
__device__ __forceinline__ unsigned short bf16r(float a) {
    unsigned int ua = __float_as_uint(a);
    return (unsigned short)((ua + 0x7fffu + ((ua >> 16) & 1u)) >> 16);
}
__device__ __forceinline__ unsigned int packh2(float a, float b) {
    return __builtin_bit_cast(unsigned int, __builtin_amdgcn_cvt_pkrtz(a, b));
}
__device__ __forceinline__ f16x2 packh2v(float a, float b) {
    return __builtin_bit_cast(f16x2, __builtin_amdgcn_cvt_pkrtz(a, b));
}
__device__ __forceinline__ float2 unpackh2(unsigned int u) {
    f16x2 h = __builtin_bit_cast(f16x2, u);
    return make_float2((float)h.x, (float)h.y);
}

// ---------------- CSR build: two-level bucketed counting sort (256-node buckets) -------
__global__ void bucket_zero_kernel(int* __restrict__ gcnt, int* __restrict__ dhist) {
    int i = blockIdx.x * 256 + threadIdx.x;
    if (i < NBUCK) gcnt[i] = 0;
    if (i < 256) dhist[i] = 0;
}

__global__ __launch_bounds__(256) void bucket_hist_kernel(const int* __restrict__ ei,
                                                          int* __restrict__ gcnt) {
    __shared__ int h[NBUCK];
    for (int i = threadIdx.x; i < NBUCK; i += 256) h[i] = 0;
    __syncthreads();
    int base = blockIdx.x * BCHUNK;
    int lim = min(base + BCHUNK, ET);
    for (int i = base + threadIdx.x; i < lim; i += 256) {
        int dst = (i < N_EDGES) ? ei[N_EDGES + i] : i - N_EDGES;
        atomicAdd(&h[dst >> 8], 1);
    }
    __syncthreads();
    for (int i = threadIdx.x; i < NBUCK; i += 256)
        if (h[i]) atomicAdd(&gcnt[i], h[i]);
}

__global__ void bucket_scan_kernel(const int* __restrict__ gcnt, int* __restrict__ bbase,
                                   int* __restrict__ bcur, int* __restrict__ rowptr) {
    __shared__ int sh[256];
    int tid = threadIdx.x;  // 256 threads
    int v = (tid < NBUCK) ? gcnt[tid] : 0;
    sh[tid] = v;
    __syncthreads();
    for (int off = 1; off < 256; off <<= 1) {
        int t = (tid >= off) ? sh[tid - off] : 0;
        __syncthreads();
        sh[tid] += t;
        __syncthreads();
    }
    if (tid < NBUCK) {
        int ex = sh[tid] - v;
        bbase[tid] = ex;
        bcur[tid] = ex;
    }
    if (tid == NBUCK - 1) bbase[NBUCK] = sh[tid];
    if (tid == 0) rowptr[N_NODES] = ET;
}

__global__ __launch_bounds__(256) void bucket_scatter_kernel(const int* __restrict__ ei,
                                                             int* __restrict__ bcur,
                                                             unsigned int* __restrict__ pairs) {
    __shared__ int h[NBUCK];
    __shared__ int rbase[NBUCK];
    for (int i = threadIdx.x; i < NBUCK; i += 256) h[i] = 0;
    __syncthreads();
    int base = blockIdx.x * BCHUNK;
    int lim = min(base + BCHUNK, ET);
    for (int i = base + threadIdx.x; i < lim; i += 256) {
        int dst = (i < N_EDGES) ? ei[N_EDGES + i] : i - N_EDGES;
        atomicAdd(&h[dst >> 8], 1);
    }
    __syncthreads();
    for (int i = threadIdx.x; i < NBUCK; i += 256) {
        rbase[i] = h[i] ? atomicAdd(&bcur[i], h[i]) : 0;
        h[i] = 0;
    }
    __syncthreads();
    for (int i = base + threadIdx.x; i < lim; i += 256) {
        int src, dst;
        if (i < N_EDGES) { src = ei[i]; dst = ei[N_EDGES + i]; }
        else { src = dst = i - N_EDGES; }
        int b = dst >> 8;
        int pos = rbase[b] + atomicAdd(&h[b], 1);
        pairs[pos] = (unsigned int)src | ((unsigned int)(dst & 255) << 16);
    }
}

__global__ __launch_bounds__(256) void bucket_sort_kernel(const unsigned int* __restrict__ pairs,
                                                          const int* __restrict__ bbase,
                                                          int* __restrict__ rowptr,
                                                          unsigned short* __restrict__ csr_src) {
    __shared__ int h[256], cur[256], sh[256];
    int b = blockIdx.x;
    int tid = threadIdx.x;
    h[tid] = 0;
    __syncthreads();
    int bs = bbase[b], be = bbase[b + 1];
    for (int i = bs + tid; i < be; i += 256) atomicAdd(&h[pairs[i] >> 16], 1);
    __syncthreads();
    int v = h[tid];
    sh[tid] = v;
    __syncthreads();
    for (int off = 1; off < 256; off <<= 1) {
        int u = (tid >= off) ? sh[tid - off] : 0;
        __syncthreads();
        sh[tid] += u;
        __syncthreads();
    }
    int ex = sh[tid] - v;
    cur[tid] = ex;
    int n0 = b * 256 + tid;
    if (n0 < N_NODES) rowptr[n0] = bs + ex;
    __syncthreads();
    for (int i = bs + tid; i < be; i += 256) {
        unsigned int u = pairs[i];
        int ln = u >> 16;
        int pos = bs + atomicAdd(&cur[ln], 1);
        csr_src[pos] = (unsigned short)(u & 0xffffu);
    }
}

// ---------------- Degree sort (two-level, LDS hist) ----------------
__global__ __launch_bounds__(256) void deg_hist_kernel(const int* __restrict__ rowptr,
                                                       int* __restrict__ dhist) {
    __shared__ int h[256];
    h[threadIdx.x] = 0;
    __syncthreads();
    int n = blockIdx.x * 256 + threadIdx.x;
    if (n < N_NODES) {
        int cc = min((rowptr[n + 1] - rowptr[n] + 7) >> 3, 255);
        atomicAdd(&h[cc], 1);
    }
    __syncthreads();
    if (h[threadIdx.x]) atomicAdd(&dhist[threadIdx.x], h[threadIdx.x]);
}

__global__ void deg_scan_kernel(const int* __restrict__ dhist, int* __restrict__ dcur) {
    __shared__ int sh[256];
    int t = threadIdx.x;
    int v = dhist[t];
    sh[t] = v;
    __syncthreads();
    for (int off = 1; off < 256; off <<= 1) {
        int u = (t >= off) ? sh[t - off] : 0;
        __syncthreads();
        sh[t] += u;
        __syncthreads();
    }
    dcur[t] = sh[t] - v;
}

__global__ __launch_bounds__(256) void deg_scatter_kernel(const int* __restrict__ rowptr,
                                                          int* __restrict__ dcur,
                                                          int* __restrict__ perm) {
    __shared__ int h[256], rbase[256];
    int t = threadIdx.x;
    h[t] = 0;
    __syncthreads();
    int n = blockIdx.x * 256 + t;
    int cc = -1;
    if (n < N_NODES) {
        cc = min((rowptr[n + 1] - rowptr[n] + 7) >> 3, 255);
        atomicAdd(&h[cc], 1);
    }
    __syncthreads();
    rbase[t] = h[t] ? atomicAdd(&dcur[t], h[t]) : 0;
    h[t] = 0;
    __syncthreads();
    if (n < N_NODES) {
        int pos = rbase[cc] + atomicAdd(&h[cc], 1);
        perm[pos] = n;
    }
}

// ---------------- Weight convert: W[k][c] f32 -> Wt[c][k] bf16, all 8 mats ----------------
__global__ __launch_bounds__(256) void wconv_kernel(const float* __restrict__ Wl,
                                                    const float* __restrict__ Wr,
                                                    unsigned short* __restrict__ wt) {
    int m = blockIdx.x;  // 0..7: layer = m>>1, mat = m&1
    const float* __restrict__ W = ((m & 1) ? Wr : Wl) + (size_t)(m >> 1) * HID * HID;
    unsigned short* __restrict__ o = wt + (size_t)m * HID * HID;
    for (int i = threadIdx.x; i < HID * HID; i += 256) {
        int k = i >> 7, c = i & 127;
        o[c * HID + k] = bf16r(W[i]);
    }
}

// ---------------- MFMA GEMM, merged + A-in-registers, W in LDS ----------------
__global__ __launch_bounds__(256) void gemm_mfma_kernel(
    const float* __restrict__ hin_f, const unsigned int* __restrict__ hin_h,
    const unsigned short* __restrict__ wt_layer,
    unsigned int* __restrict__ xlh, unsigned int* __restrict__ xrh,
    const float* __restrict__ scale, const float* __restrict__ shift, int donorm) {
    __shared__ unsigned int Wsh[128 * 64];  // 32KB
    int row0 = blockIdx.x * 64;
    int tid = threadIdx.x;
    int w = tid >> 6, l = tid & 63;
    int lr = l & 15, lk = l >> 4;
    int node = row0 + w * 16 + lr;
    bool valid = node < N_NODES;

    bfx8 afrag[4];
#pragma unroll
    for (int kt = 0; kt < 4; kt++) {
        int ch = kt * 4 + lk;
        float4 va = make_float4(0.f, 0.f, 0.f, 0.f), vb = va;
        if (valid) {
            if (hin_h) {
                uint4 u = *(const uint4*)(hin_h + (size_t)node * 64 + ch * 4);
                float2 f0 = unpackh2(u.x), f1 = unpackh2(u.y);
                float2 f2 = unpackh2(u.z), f3 = unpackh2(u.w);
                va = make_float4(f0.x, f0.y, f1.x, f1.y);
                vb = make_float4(f2.x, f2.y, f3.x, f3.y);
            } else {
                const float4* src = (const float4*)(hin_f + (size_t)node * HID + ch * 8);
                va = src[0]; vb = src[1];
            }
            if (donorm) {
                const float4* s4 = (const float4*)(scale + ch * 8);
                const float4* t4 = (const float4*)(shift + ch * 8);
                float4 s0 = s4[0], s1 = s4[1], t0 = t4[0], t1 = t4[1];
                va.x = va.x * s0.x + t0.x; va.y = va.y * s0.y + t0.y;
                va.z = va.z * s0.z + t0.z; va.w = va.w * s0.w + t0.w;
                vb.x = vb.x * s1.x + t1.x; vb.y = vb.y * s1.y + t1.y;
                vb.z = vb.z * s1.z + t1.z; vb.w = vb.w * s1.w + t1.w;
            }
        }
        unsigned int pk0 = packbf2(va.x, va.y), pk1 = packbf2(va.z, va.w);
        unsigned int pk2 = packbf2(vb.x, vb.y), pk3 = packbf2(vb.z, vb.w);
        uint4 pk = make_uint4(pk0, pk1, pk2, pk3);
        afrag[kt] = __builtin_bit_cast(bfx8, pk);
    }

    for (int mat = 0; mat < 2; mat++) {
        if (mat) __syncthreads();
        const uint4* wm4 = (const uint4*)(wt_layer + (size_t)mat * HID * HID);
        for (int i = tid; i < 2048; i += 256) {
            int c = i >> 4, ch = i & 15;
            uint4 v = wm4[i];
            *(uint4*)(&Wsh[c * 64 + ((ch ^ (c & 7)) << 2)]) = v;
        }
        __syncthreads();

        fx4 acc[8];
#pragma unroll
        for (int ct = 0; ct < 8; ct++) acc[ct] = (fx4){0.f, 0.f, 0.f, 0.f};
#pragma unroll
        for (int kt = 0; kt < 4; kt++) {
            int ch = kt * 4 + lk;
#pragma unroll
            for (int ct = 0; ct < 8; ct++) {
                int c = ct * 16 + lr;
                bfx8 aw = __builtin_bit_cast(bfx8, *(const s16x8*)(&Wsh[c * 64 + ((ch ^ (c & 7)) << 2)]));
                acc[ct] = __builtin_amdgcn_mfma_f32_16x16x32_bf16(aw, afrag[kt], acc[ct], 0, 0, 0);
            }
        }
        unsigned int* o = mat ? xrh : xlh;
        if (valid) {
#pragma unroll
            for (int ct = 0; ct < 8; ct++) {
                int cb = ct * 8 + lk * 2;
                uint2 p0;
                p0.x = packh2(acc[ct][0], acc[ct][1]);
                p0.y = packh2(acc[ct][2], acc[ct][3]);
                *(uint2*)(o + (size_t)node * 64 + cb) = p0;
            }
        }
    }
}

// ---------------- Edge aggregation: persistent grid-stride, LPT order --------------
__global__ __launch_bounds__(256) void aggregate_kernel(
    const unsigned int* __restrict__ xlh, const unsigned int* __restrict__ xrh,
    const float* __restrict__ att, const float* __restrict__ bias,
    const int* __restrict__ rowptr, const unsigned short* __restrict__ csr_src,
    const int* __restrict__ perm, unsigned int* __restrict__ hout) {
    int g = threadIdx.x & 15;    // lane within group
    int c0 = g * 8;              // 8 cols per lane
    // slot-invariant per-lane constants (hoisted)
    float4 aa = *(const float4*)(att + c0);
    float4 ab = *(const float4*)(att + c0 + 4);
    f16x2 a0 = packh2v(aa.x * LOG2E, aa.y * LOG2E);
    f16x2 a1 = packh2v(aa.z * LOG2E, aa.w * LOG2E);
    f16x2 a2 = packh2v(ab.x * LOG2E, ab.y * LOG2E);
    f16x2 a3 = packh2v(ab.z * LOG2E, ab.w * LOG2E);
    float4 ba = *(const float4*)(bias + c0);
    float4 bb = *(const float4*)(bias + c0 + 4);
    const f16x2 negc = {(_Float16)NEG, (_Float16)NEG};
    bool b0 = (g & 1) != 0, b1 = (g & 2) != 0, b2 = (g & 4) != 0;
    int myj = g & 7;
    const int NG = AGG_BLOCKS * 16;  // total groups

    for (int slot = blockIdx.x * 16 + (threadIdx.x >> 4); slot < N_NODES; slot += NG) {
        int node = perm[N_NODES - 1 - slot];  // LPT: biggest nodes first
        const uint4 ru = *(const uint4*)(xrh + (size_t)node * 64 + g * 4);
        f16x2 r0 = __builtin_bit_cast(f16x2, ru.x), r1 = __builtin_bit_cast(f16x2, ru.y);
        f16x2 r2 = __builtin_bit_cast(f16x2, ru.z), r3 = __builtin_bit_cast(f16x2, ru.w);
        int beg = rowptr[node], end = rowptr[node + 1];
        float spart = 0.f;
        float acc0 = 0.f, acc1 = 0.f, acc2 = 0.f, acc3 = 0.f;
        float acc4 = 0.f, acc5 = 0.f, acc6 = 0.f, acc7 = 0.f;
        int idxc = (int)csr_src[min(beg + myj, end - 1)];
        for (int base = beg; base < end; base += 8) {
            int nn = end - base;
            if (nn > 8) nn = 8;
            int idxn = (base + 8 < end) ? (int)csr_src[min(base + 8 + myj, end - 1)] : 0;
            uint4 v[8];
#pragma unroll
            for (int j = 0; j < 8; j++) {
                int sj = __shfl(idxc, j, 8);
                v[j] = *(const uint4*)(xlh + (size_t)sj * 64 + g * 4);
            }
            float p[8];
#pragma unroll
            for (int j = 0; j < 8; j++) {
                f16x2 v0 = __builtin_bit_cast(f16x2, v[j].x);
                f16x2 v1 = __builtin_bit_cast(f16x2, v[j].y);
                f16x2 v2 = __builtin_bit_cast(f16x2, v[j].z);
                f16x2 v3 = __builtin_bit_cast(f16x2, v[j].w);
                f16x2 s0 = v0 + r0, s1 = v1 + r1, s2 = v2 + r2, s3 = v3 + r3;
                f16x2 m0 = __builtin_elementwise_max(s0, s0 * negc);
                f16x2 m1 = __builtin_elementwise_max(s1, s1 * negc);
                f16x2 m2 = __builtin_elementwise_max(s2, s2 * negc);
                f16x2 m3 = __builtin_elementwise_max(s3, s3 * negc);
                p[j] = __builtin_amdgcn_fdot2(m0, a0,
                         __builtin_amdgcn_fdot2(m1, a1,
                           __builtin_amdgcn_fdot2(m2, a2,
                             __builtin_amdgcn_fdot2(m3, a3, 0.f, false), false), false), false);
            }
            // tree reduce 8 values over 16 lanes; lane ends with sum for edge (g&7)
            float q0 = (b0 ? p[1] : p[0]) + __shfl_xor(b0 ? p[0] : p[1], 1);
            float q1 = (b0 ? p[3] : p[2]) + __shfl_xor(b0 ? p[2] : p[3], 1);
            float q2 = (b0 ? p[5] : p[4]) + __shfl_xor(b0 ? p[4] : p[5], 1);
            float q3 = (b0 ? p[7] : p[6]) + __shfl_xor(b0 ? p[6] : p[7], 1);
            float t0 = (b1 ? q1 : q0) + __shfl_xor(b1 ? q0 : q1, 2);
            float t1 = (b1 ? q3 : q2) + __shfl_xor(b1 ? q2 : q3, 2);
            float f  = (b2 ? t1 : t0) + __shfl_xor(b2 ? t0 : t1, 4);
            f += __shfl_xor(f, 8);
            float wown = (myj < nn) ? exp2f(f) : 0.f;  // fixed-base softmax weight
            spart += wown;
#pragma unroll
            for (int j = 0; j < 8; j++) {
                float wj = __shfl(wown, j, 8);
                f16x2 v0 = __builtin_bit_cast(f16x2, v[j].x);
                f16x2 v1 = __builtin_bit_cast(f16x2, v[j].y);
                f16x2 v2 = __builtin_bit_cast(f16x2, v[j].z);
                f16x2 v3 = __builtin_bit_cast(f16x2, v[j].w);
                acc0 += wj * (float)v0.x; acc1 += wj * (float)v0.y;
                acc2 += wj * (float)v1.x; acc3 += wj * (float)v1.y;
                acc4 += wj * (float)v2.x; acc5 += wj * (float)v2.y;
                acc6 += wj * (float)v3.x; acc7 += wj * (float)v3.y;
            }
            idxc = idxn;
        }
        float s = spart;
        s += __shfl_xor(s, 1);
        s += __shfl_xor(s, 2);
        s += __shfl_xor(s, 4);
        float inv = 1.f / s;
        uint4 po;
        po.x = packh2(acc0 * inv + ba.x, acc1 * inv + ba.y);
        po.y = packh2(acc2 * inv + ba.z, acc3 * inv + ba.w);
        po.z = packh2(acc4 * inv + bb.x, acc5 * inv + bb.y);
        po.w = packh2(acc6 * inv + bb.z, acc7 * inv + bb.w);
        *(uint4*)(hout + (size_t)node * 64 + g * 4) = po;
    }
}

// ---------------- BatchNorm stats (h in f16) ----------------
__global__ __launch_bounds__(256) void bn_reduce_kernel(const unsigned int* __restrict__ h,
                                                        float* __restrict__ part) {
    int tid = threadIdx.x;
    int cu = tid & 63, half = tid >> 6;
    float s0 = 0.f, q0 = 0.f, s1 = 0.f, q1 = 0.f;
    for (int r = blockIdx.x * 4 + half; r < N_NODES; r += RB * 4) {
        float2 v = unpackh2(h[(size_t)r * 64 + cu]);
        s0 += v.x; q0 += v.x * v.x;
        s1 += v.y; q1 += v.y * v.y;
    }
    __shared__ float sh[256];
    sh[half * 64 + cu] = s0;
    __syncthreads();
    if (tid < 64) {
        float r0 = sh[tid] + sh[64 + tid] + sh[128 + tid] + sh[192 + tid];
        part[blockIdx.x * 256 + tid * 2] = r0;
    }
    __syncthreads();
    sh[half * 64 + cu] = q0;
    __syncthreads();
    if (tid < 64) {
        float r0 = sh[tid] + sh[64 + tid] + sh[128 + tid] + sh[192 + tid];
        part[blockIdx.x * 256 + 128 + tid * 2] = r0;
    }
    __syncthreads();
    sh[half * 64 + cu] = s1;
    __syncthreads();
    if (tid < 64) {
        float r0 = sh[tid] + sh[64 + tid] + sh[128 + tid] + sh[192 + tid];
        part[blockIdx.x * 256 + tid * 2 + 1] = r0;
    }
    __syncthreads();
    sh[half * 64 + cu] = q1;
    __syncthreads();
    if (tid < 64) {
        float r0 = sh[tid] + sh[64 + tid] + sh[128 + tid] + sh[192 + tid];
        part[blockIdx.x * 256 + 128 + tid * 2 + 1] = r0;
    }
}

__global__ void bn_finalize_kernel(const float* __restrict__ part,
                                   const float* __restrict__ gamma,
                                   const float* __restrict__ beta,
                                   float* __restrict__ scale, float* __restrict__ shift) {
    int c = threadIdx.x;  // 128 threads
    float s = 0.f, q = 0.f;
    for (int b = 0; b < RB; b++) {
        s += part[b * 256 + c];
        q += part[b * 256 + 128 + c];
    }
    float m = s / (float)N_NODES;
    float v = q / (float)N_NODES - m * m;
    if (v < 0.f) v = 0.f;
    float rs = rsqrtf(v + EPS);
    float sc = rs * gamma[c];
    scale[c] = sc;
    shift[c] = beta[c] - m * sc;
}

// ---------------- Decode: residual sum on the fly + dot product ----------------
__global__ __launch_bounds__(256) void predict_kernel(const unsigned int* __restrict__ hb,
                                                      const float* __restrict__ scale4,
                                                      const float* __restrict__ shift4,
                                                      const int* __restrict__ eli,
                                                      float* __restrict__ out) {
    int p = blockIdx.x * 4 + (threadIdx.x >> 6);
    if (p >= 8192) return;
    int lane = threadIdx.x & 63;
    int i = eli[p], j = eli[8192 + p];
    int c = lane * 2;
    float ai0 = 0.f, ai1 = 0.f, aj0 = 0.f, aj1 = 0.f;
#pragma unroll
    for (int l = 0; l < N_LAYERS; l++) {
        float sc0 = scale4[l * HID + c], sc1 = scale4[l * HID + c + 1];
        float sh0 = shift4[l * HID + c], sh1 = shift4[l * HID + c + 1];
        float2 vi = unpackh2(hb[(size_t)l * N_NODES * 64 + (size_t)i * 64 + lane]);
        float2 vj = unpackh2(hb[(size_t)l * N_NODES * 64 + (size_t)j * 64 + lane]);
        ai0 += vi.x * sc0 + sh0; ai1 += vi.y * sc1 + sh1;
        aj0 += vj.x * sc0 + sh0; aj1 += vj.y * sc1 + sh1;
    }
    float t = 0.04f * (ai0 * aj0 + ai1 * aj1);  // resw^2 = 0.2^2
#pragma unroll
    for (int off = 32; off; off >>= 1) t += __shfl_xor(t, off, 64);
    if (lane == 0) out[p] = t;
}

extern "C" void kernel_launch(void* const* d_in, const int* in_sizes, int n_in,
                              void* d_out, int out_size, void* d_ws, size_t ws_size,
                              hipStream_t stream) {
    const float* x = (const float*)d_in[0];
    const int* ei = (const int*)d_in[1];
    const int* eli = (const int*)d_in[2];
    const float* Wl = (const float*)d_in[3];
    const float* Wr = (const float*)d_in[4];
    const float* att = (const float*)d_in[5];
    const float* bias = (const float*)d_in[6];
    const float* gamma = (const float*)d_in[7];
    const float* beta = (const float*)d_in[8];
    float* out = (float*)d_out;

    char* ws = (char*)d_ws;
    size_t off = 0;
    unsigned int* hb   = (unsigned int*)(ws + off); off += (size_t)N_LAYERS * N_NODES * HID * 2;  // 4 x f16 h
    unsigned int* xlh  = (unsigned int*)(ws + off); off += (size_t)N_NODES * HID * 2;  // f16
    unsigned int* xrh  = (unsigned int*)(ws + off); off += (size_t)N_NODES * HID * 2;  // f16
    int* rowptr = (int*)(ws + off);   off += ((size_t)(N_NODES + 1) * 4 + 31) & ~31ul;
    unsigned short* csr_src = (unsigned short*)(ws + off); off += ((size_t)(ET + 16) * 2 + 31) & ~31ul;
    int* gcnt  = (int*)(ws + off);    off += (size_t)(NBUCK + 8) * 4;
    int* bcur  = (int*)(ws + off);    off += (size_t)(NBUCK + 8) * 4;
    int* bbase = (int*)(ws + off);    off += (size_t)(NBUCK + 8) * 4;
    int* dhist = (int*)(ws + off);    off += 256 * 4;
    int* dcur  = (int*)(ws + off);    off += 256 * 4;
    int* perm  = (int*)(ws + off);    off += (size_t)N_NODES * 4;
    float* part = (float*)(ws + off); off += (size_t)RB * 256 * 4;
    float* scale4 = (float*)(ws + off); off += (size_t)N_LAYERS * 128 * 4;
    float* shift4 = (float*)(ws + off); off += (size_t)N_LAYERS * 128 * 4;
    unsigned short* wt = (unsigned short*)(ws + off); off += (size_t)8 * HID * HID * 2;
    unsigned int* pairs = (unsigned int*)(ws + off); off += (size_t)ET * 4;  // CSR temp

    // One-time: weights -> bf16 transposed [layer][mat][col][k]
    wconv_kernel<<<8, 256, 0, stream>>>(Wl, Wr, wt);

    // CSR build (dst-sorted), bucketed counting sort; topology fixed across layers
    int nablk = (ET + BCHUNK - 1) / BCHUNK;
    bucket_zero_kernel<<<1, 256, 0, stream>>>(gcnt, dhist);
    bucket_hist_kernel<<<nablk, 256, 0, stream>>>(ei, gcnt);
    bucket_scan_kernel<<<1, 256, 0, stream>>>(gcnt, bbase, bcur, rowptr);
    bucket_scatter_kernel<<<nablk, 256, 0, stream>>>(ei, bcur, pairs);
    bucket_sort_kernel<<<NBUCK, 256, 0, stream>>>(pairs, bbase, rowptr, csr_src);

    // Degree-sorted node permutation (divergence fix for aggregate)
    deg_hist_kernel<<<(N_NODES + 255) / 256, 256, 0, stream>>>(rowptr, dhist);
    deg_scan_kernel<<<1, 256, 0, stream>>>(dhist, dcur);
    deg_scatter_kernel<<<(N_NODES + 255) / 256, 256, 0, stream>>>(rowptr, dcur, perm);

    for (int l = 0; l < N_LAYERS; l++) {
        int donorm = (l == 0) ? 0 : 1;
        const unsigned int* hin_h = (l == 0) ? nullptr : hb + (size_t)(l - 1) * N_NODES * 64;
        gemm_mfma_kernel<<<(N_NODES + 63) / 64, 256, 0, stream>>>(
            (l == 0) ? x : nullptr, hin_h,
            wt + (size_t)l * 2 * HID * HID, xlh, xrh,
            scale4 + (size_t)(l ? l - 1 : 0) * HID, shift4 + (size_t)(l ? l - 1 : 0) * HID,
            donorm);
        aggregate_kernel<<<AGG_BLOCKS, 256, 0, stream>>>(
            xlh, xrh, att + l * HID, bias + l * HID, rowptr, csr_src, perm,
            hb + (size_t)l * N_NODES * 64);
        bn_reduce_kernel<<<RB, 256, 0, stream>>>(hb + (size_t)l * N_NODES * 64, part);
        bn_finalize_kernel<<<1, 128, 0, stream>>>(part, gamma + l * HID, beta + l * HID,
                                                  scale4 + (size_t)l * HID,
                                                  shift4 + (size_t)l * HID);
    }
    predict_kernel<<<8192 / 4, 256, 0, stream>>>(hb, scale4, shift4, eli, out);
}

// Round 20
// 481.434 us; speedup vs baseline: 1.0076x; 1.0076x over previous
//
#include <hip/hip_runtime.h>
#include <hip/hip_bf16.h>
#include <hip/hip_fp16.h>

#define N_NODES 50000
#define N_EDGES 1600000
#define ET (N_EDGES + N_NODES)
#define HID 128
#define N_LAYERS 4
#define EPS 1e-5f
#define NEG 0.2f
#define RB 256      // bn reduce blocks
#define NBUCK 196   // ceil(N_NODES/256), 256-node buckets
#define BCHUNK 8192
#define LOG2E 1.44269504088896f
#define AGG_BLOCKS 2048

typedef __attribute__((ext_vector_type(8))) short s16x8;
typedef __attribute__((ext_vector_type(8))) __bf16 bfx8;
typedef __attribute__((ext_vector_type(4))) float fx4;
typedef __attribute__((ext_vector_type(2))) _Float16 f16x2;

__device__ __forceinline__ unsigned int packbf2(float a, float b) {
    unsigned int ua = __float_as_uint(a);
    ua = (ua + 0x7fffu + ((ua >> 16) & 1u)) >> 16;
    unsigned int ub = __float_as_uint(b);
    ub = (ub + 0x7fffu + ((ub >> 16) & 1u)) & 0xffff0000u;
    return (ua & 0xffffu) | ub;
}
__device__ __forceinline__ unsigned short bf16r(float a) {
    unsigned int ua = __float_as_uint(a);
    return (unsigned short)((ua + 0x7fffu + ((ua >> 16) & 1u)) >> 16);
}
__device__ __forceinline__ unsigned int packh2(float a, float b) {
    return __builtin_bit_cast(unsigned int, __builtin_amdgcn_cvt_pkrtz(a, b));
}
__device__ __forceinline__ f16x2 packh2v(float a, float b) {
    return __builtin_bit_cast(f16x2, __builtin_amdgcn_cvt_pkrtz(a, b));
}
__device__ __forceinline__ float2 unpackh2(unsigned int u) {
    f16x2 h = __builtin_bit_cast(f16x2, u);
    return make_float2((float)h.x, (float)h.y);
}

// ---------------- CSR build: two-level bucketed counting sort (256-node buckets) -------
__global__ void bucket_zero_kernel(int* __restrict__ gcnt, int* __restrict__ dhist) {
    int i = blockIdx.x * 256 + threadIdx.x;
    if (i < NBUCK) gcnt[i] = 0;
    if (i < 256) dhist[i] = 0;
}

__global__ __launch_bounds__(256) void bucket_hist_kernel(const int* __restrict__ ei,
                                                          int* __restrict__ gcnt) {
    __shared__ int h[NBUCK];
    for (int i = threadIdx.x; i < NBUCK; i += 256) h[i] = 0;
    __syncthreads();
    int base = blockIdx.x * BCHUNK;
    int lim = min(base + BCHUNK, ET);
    for (int i = base + threadIdx.x; i < lim; i += 256) {
        int dst = (i < N_EDGES) ? ei[N_EDGES + i] : i - N_EDGES;
        atomicAdd(&h[dst >> 8], 1);
    }
    __syncthreads();
    for (int i = threadIdx.x; i < NBUCK; i += 256)
        if (h[i]) atomicAdd(&gcnt[i], h[i]);
}

__global__ void bucket_scan_kernel(const int* __restrict__ gcnt, int* __restrict__ bbase,
                                   int* __restrict__ bcur, int* __restrict__ rowptr) {
    __shared__ int sh[256];
    int tid = threadIdx.x;  // 256 threads
    int v = (tid < NBUCK) ? gcnt[tid] : 0;
    sh[tid] = v;
    __syncthreads();
    for (int off = 1; off < 256; off <<= 1) {
        int t = (tid >= off) ? sh[tid - off] : 0;
        __syncthreads();
        sh[tid] += t;
        __syncthreads();
    }
    if (tid < NBUCK) {
        int ex = sh[tid] - v;
        bbase[tid] = ex;
        bcur[tid] = ex;
    }
    if (tid == NBUCK - 1) bbase[NBUCK] = sh[tid];
    if (tid == 0) rowptr[N_NODES] = ET;
}

__global__ __launch_bounds__(256) void bucket_scatter_kernel(const int* __restrict__ ei,
                                                             int* __restrict__ bcur,
                                                             unsigned int* __restrict__ pairs) {
    __shared__ int h[NBUCK];
    __shared__ int rbase[NBUCK];
    for (int i = threadIdx.x; i < NBUCK; i += 256) h[i] = 0;
    __syncthreads();
    int base = blockIdx.x * BCHUNK;
    int lim = min(base + BCHUNK, ET);
    for (int i = base + threadIdx.x; i < lim; i += 256) {
        int dst = (i < N_EDGES) ? ei[N_EDGES + i] : i - N_EDGES;
        atomicAdd(&h[dst >> 8], 1);
    }
    __syncthreads();
    for (int i = threadIdx.x; i < NBUCK; i += 256) {
        rbase[i] = h[i] ? atomicAdd(&bcur[i], h[i]) : 0;
        h[i] = 0;
    }
    __syncthreads();
    for (int i = base + threadIdx.x; i < lim; i += 256) {
        int src, dst;
        if (i < N_EDGES) { src = ei[i]; dst = ei[N_EDGES + i]; }
        else { src = dst = i - N_EDGES; }
        int b = dst >> 8;
        int pos = rbase[b] + atomicAdd(&h[b], 1);
        pairs[pos] = (unsigned int)src | ((unsigned int)(dst & 255) << 16);
    }
}

__global__ __launch_bounds__(256) void bucket_sort_kernel(const unsigned int* __restrict__ pairs,
                                                          const int* __restrict__ bbase,
                                                          int* __restrict__ rowptr,
                                                          unsigned short* __restrict__ csr_src) {
    __shared__ int h[256], cur[256], sh[256];
    int b = blockIdx.x;
    int tid = threadIdx.x;
    h[tid] = 0;
    __syncthreads();
    int bs = bbase[b], be = bbase[b + 1];
    for (int i = bs + tid; i < be; i += 256) atomicAdd(&h[pairs[i] >> 16], 1);
    __syncthreads();
    int v = h[tid];
    sh[tid] = v;
    __syncthreads();
    for (int off = 1; off < 256; off <<= 1) {
        int u = (tid >= off) ? sh[tid - off] : 0;
        __syncthreads();
        sh[tid] += u;
        __syncthreads();
    }
    int ex = sh[tid] - v;
    cur[tid] = ex;
    int n0 = b * 256 + tid;
    if (n0 < N_NODES) rowptr[n0] = bs + ex;
    __syncthreads();
    for (int i = bs + tid; i < be; i += 256) {
        unsigned int u = pairs[i];
        int ln = u >> 16;
        int pos = bs + atomicAdd(&cur[ln], 1);
        csr_src[pos] = (unsigned short)(u & 0xffffu);
    }
}

// ---------------- Degree sort (two-level, LDS hist) ----------------
__global__ __launch_bounds__(256) void deg_hist_kernel(const int* __restrict__ rowptr,
                                                       int* __restrict__ dhist) {
    __shared__ int h[256];
    h[threadIdx.x] = 0;
    __syncthreads();
    int n = blockIdx.x * 256 + threadIdx.x;
    if (n < N_NODES) {
        int cc = min((rowptr[n + 1] - rowptr[n] + 7) >> 3, 255);
        atomicAdd(&h[cc], 1);
    }
    __syncthreads();
    if (h[threadIdx.x]) atomicAdd(&dhist[threadIdx.x], h[threadIdx.x]);
}

__global__ void deg_scan_kernel(const int* __restrict__ dhist, int* __restrict__ dcur) {
    __shared__ int sh[256];
    int t = threadIdx.x;
    int v = dhist[t];
    sh[t] = v;
    __syncthreads();
    for (int off = 1; off < 256; off <<= 1) {
        int u = (t >= off) ? sh[t - off] : 0;
        __syncthreads();
        sh[t] += u;
        __syncthreads();
    }
    dcur[t] = sh[t] - v;
}

__global__ __launch_bounds__(256) void deg_scatter_kernel(const int* __restrict__ rowptr,
                                                          int* __restrict__ dcur,
                                                          int* __restrict__ perm) {
    __shared__ int h[256], rbase[256];
    int t = threadIdx.x;
    h[t] = 0;
    __syncthreads();
    int n = blockIdx.x * 256 + t;
    int cc = -1;
    if (n < N_NODES) {
        cc = min((rowptr[n + 1] - rowptr[n] + 7) >> 3, 255);
        atomicAdd(&h[cc], 1);
    }
    __syncthreads();
    rbase[t] = h[t] ? atomicAdd(&dcur[t], h[t]) : 0;
    h[t] = 0;
    __syncthreads();
    if (n < N_NODES) {
        int pos = rbase[cc] + atomicAdd(&h[cc], 1);
        perm[pos] = n;
    }
}

// ---------------- Weight convert: W[k][c] f32 -> Wt[c][k] bf16, all 8 mats ----------------
__global__ __launch_bounds__(256) void wconv_kernel(const float* __restrict__ Wl,
                                                    const float* __restrict__ Wr,
                                                    unsigned short* __restrict__ wt) {
    int m = blockIdx.x;  // 0..7: layer = m>>1, mat = m&1
    const float* __restrict__ W = ((m & 1) ? Wr : Wl) + (size_t)(m >> 1) * HID * HID;
    unsigned short* __restrict__ o = wt + (size_t)m * HID * HID;
    for (int i = threadIdx.x; i < HID * HID; i += 256) {
        int k = i >> 7, c = i & 127;
        o[c * HID + k] = bf16r(W[i]);
    }
}

// ---------------- MFMA GEMM: 128 nodes/block (8 waves), A-in-registers, W in LDS -------
__global__ __launch_bounds__(512) void gemm_mfma_kernel(
    const float* __restrict__ hin_f, const unsigned int* __restrict__ hin_h,
    const unsigned short* __restrict__ wt_layer,
    unsigned int* __restrict__ xlh, unsigned int* __restrict__ xrh,
    const float* __restrict__ scale, const float* __restrict__ shift, int donorm) {
    __shared__ unsigned int Wsh[128 * 64];  // 32KB
    int row0 = blockIdx.x * 128;
    int tid = threadIdx.x;
    int w = tid >> 6, l = tid & 63;
    int lr = l & 15, lk = l >> 4;
    int node = row0 + w * 16 + lr;
    bool valid = node < N_NODES;

    bfx8 afrag[4];
#pragma unroll
    for (int kt = 0; kt < 4; kt++) {
        int ch = kt * 4 + lk;
        float4 va = make_float4(0.f, 0.f, 0.f, 0.f), vb = va;
        if (valid) {
            if (hin_h) {
                uint4 u = *(const uint4*)(hin_h + (size_t)node * 64 + ch * 4);
                float2 f0 = unpackh2(u.x), f1 = unpackh2(u.y);
                float2 f2 = unpackh2(u.z), f3 = unpackh2(u.w);
                va = make_float4(f0.x, f0.y, f1.x, f1.y);
                vb = make_float4(f2.x, f2.y, f3.x, f3.y);
            } else {
                const float4* src = (const float4*)(hin_f + (size_t)node * HID + ch * 8);
                va = src[0]; vb = src[1];
            }
            if (donorm) {
                const float4* s4 = (const float4*)(scale + ch * 8);
                const float4* t4 = (const float4*)(shift + ch * 8);
                float4 s0 = s4[0], s1 = s4[1], t0 = t4[0], t1 = t4[1];
                va.x = va.x * s0.x + t0.x; va.y = va.y * s0.y + t0.y;
                va.z = va.z * s0.z + t0.z; va.w = va.w * s0.w + t0.w;
                vb.x = vb.x * s1.x + t1.x; vb.y = vb.y * s1.y + t1.y;
                vb.z = vb.z * s1.z + t1.z; vb.w = vb.w * s1.w + t1.w;
            }
        }
        unsigned int pk0 = packbf2(va.x, va.y), pk1 = packbf2(va.z, va.w);
        unsigned int pk2 = packbf2(vb.x, vb.y), pk3 = packbf2(vb.z, vb.w);
        uint4 pk = make_uint4(pk0, pk1, pk2, pk3);
        afrag[kt] = __builtin_bit_cast(bfx8, pk);
    }

    for (int mat = 0; mat < 2; mat++) {
        if (mat) __syncthreads();
        const uint4* wm4 = (const uint4*)(wt_layer + (size_t)mat * HID * HID);
        for (int i = tid; i < 2048; i += 512) {
            int c = i >> 4, ch = i & 15;
            uint4 v = wm4[i];
            *(uint4*)(&Wsh[c * 64 + ((ch ^ (c & 7)) << 2)]) = v;
        }
        __syncthreads();

        fx4 acc[8];
#pragma unroll
        for (int ct = 0; ct < 8; ct++) acc[ct] = (fx4){0.f, 0.f, 0.f, 0.f};
#pragma unroll
        for (int kt = 0; kt < 4; kt++) {
            int ch = kt * 4 + lk;
#pragma unroll
            for (int ct = 0; ct < 8; ct++) {
                int c = ct * 16 + lr;
                bfx8 aw = __builtin_bit_cast(bfx8, *(const s16x8*)(&Wsh[c * 64 + ((ch ^ (c & 7)) << 2)]));
                acc[ct] = __builtin_amdgcn_mfma_f32_16x16x32_bf16(aw, afrag[kt], acc[ct], 0, 0, 0);
            }
        }
        unsigned int* o = mat ? xrh : xlh;
        if (valid) {
#pragma unroll
            for (int ct = 0; ct < 8; ct++) {
                int cb = ct * 8 + lk * 2;
                uint2 p0;
                p0.x = packh2(acc[ct][0], acc[ct][1]);
                p0.y = packh2(acc[ct][2], acc[ct][3]);
                *(uint2*)(o + (size_t)node * 64 + cb) = p0;
            }
        }
    }
}

// ---------------- Edge aggregation: persistent grid-stride, LPT order --------------
__global__ __launch_bounds__(256) void aggregate_kernel(
    const unsigned int* __restrict__ xlh, const unsigned int* __restrict__ xrh,
    const float* __restrict__ att, const float* __restrict__ bias,
    const int* __restrict__ rowptr, const unsigned short* __restrict__ csr_src,
    const int* __restrict__ perm, unsigned int* __restrict__ hout) {
    int g = threadIdx.x & 15;    // lane within group
    int c0 = g * 8;              // 8 cols per lane
    float4 aa = *(const float4*)(att + c0);
    float4 ab = *(const float4*)(att + c0 + 4);
    f16x2 a0 = packh2v(aa.x * LOG2E, aa.y * LOG2E);
    f16x2 a1 = packh2v(aa.z * LOG2E, aa.w * LOG2E);
    f16x2 a2 = packh2v(ab.x * LOG2E, ab.y * LOG2E);
    f16x2 a3 = packh2v(ab.z * LOG2E, ab.w * LOG2E);
    float4 ba = *(const float4*)(bias + c0);
    float4 bb = *(const float4*)(bias + c0 + 4);
    const f16x2 negc = {(_Float16)NEG, (_Float16)NEG};
    bool b0 = (g & 1) != 0, b1 = (g & 2) != 0, b2 = (g & 4) != 0;
    int myj = g & 7;
    const int NG = AGG_BLOCKS * 16;  // total groups

    for (int slot = blockIdx.x * 16 + (threadIdx.x >> 4); slot < N_NODES; slot += NG) {
        int node = perm[N_NODES - 1 - slot];  // LPT: biggest nodes first
        const uint4 ru = *(const uint4*)(xrh + (size_t)node * 64 + g * 4);
        f16x2 r0 = __builtin_bit_cast(f16x2, ru.x), r1 = __builtin_bit_cast(f16x2, ru.y);
        f16x2 r2 = __builtin_bit_cast(f16x2, ru.z), r3 = __builtin_bit_cast(f16x2, ru.w);
        int beg = rowptr[node], end = rowptr[node + 1];
        float spart = 0.f;
        float acc0 = 0.f, acc1 = 0.f, acc2 = 0.f, acc3 = 0.f;
        float acc4 = 0.f, acc5 = 0.f, acc6 = 0.f, acc7 = 0.f;
        int idxc = (int)csr_src[min(beg + myj, end - 1)];
        for (int base = beg; base < end; base += 8) {
            int nn = end - base;
            if (nn > 8) nn = 8;
            int idxn = (base + 8 < end) ? (int)csr_src[min(base + 8 + myj, end - 1)] : 0;
            uint4 v[8];
#pragma unroll
            for (int j = 0; j < 8; j++) {
                int sj = __shfl(idxc, j, 8);
                v[j] = *(const uint4*)(xlh + (size_t)sj * 64 + g * 4);
            }
            float p[8];
#pragma unroll
            for (int j = 0; j < 8; j++) {
                f16x2 v0 = __builtin_bit_cast(f16x2, v[j].x);
                f16x2 v1 = __builtin_bit_cast(f16x2, v[j].y);
                f16x2 v2 = __builtin_bit_cast(f16x2, v[j].z);
                f16x2 v3 = __builtin_bit_cast(f16x2, v[j].w);
                f16x2 s0 = v0 + r0, s1 = v1 + r1, s2 = v2 + r2, s3 = v3 + r3;
                f16x2 m0 = __builtin_elementwise_max(s0, s0 * negc);
                f16x2 m1 = __builtin_elementwise_max(s1, s1 * negc);
                f16x2 m2 = __builtin_elementwise_max(s2, s2 * negc);
                f16x2 m3 = __builtin_elementwise_max(s3, s3 * negc);
                p[j] = __builtin_amdgcn_fdot2(m0, a0,
                         __builtin_amdgcn_fdot2(m1, a1,
                           __builtin_amdgcn_fdot2(m2, a2,
                             __builtin_amdgcn_fdot2(m3, a3, 0.f, false), false), false), false);
            }
            float q0 = (b0 ? p[1] : p[0]) + __shfl_xor(b0 ? p[0] : p[1], 1);
            float q1 = (b0 ? p[3] : p[2]) + __shfl_xor(b0 ? p[2] : p[3], 1);
            float q2 = (b0 ? p[5] : p[4]) + __shfl_xor(b0 ? p[4] : p[5], 1);
            float q3 = (b0 ? p[7] : p[6]) + __shfl_xor(b0 ? p[6] : p[7], 1);
            float t0 = (b1 ? q1 : q0) + __shfl_xor(b1 ? q0 : q1, 2);
            float t1 = (b1 ? q3 : q2) + __shfl_xor(b1 ? q2 : q3, 2);
            float f  = (b2 ? t1 : t0) + __shfl_xor(b2 ? t0 : t1, 4);
            f += __shfl_xor(f, 8);
            float wown = (myj < nn) ? exp2f(f) : 0.f;  // fixed-base softmax weight
            spart += wown;
#pragma unroll
            for (int j = 0; j < 8; j++) {
                float wj = __shfl(wown, j, 8);
                f16x2 v0 = __builtin_bit_cast(f16x2, v[j].x);
                f16x2 v1 = __builtin_bit_cast(f16x2, v[j].y);
                f16x2 v2 = __builtin_bit_cast(f16x2, v[j].z);
                f16x2 v3 = __builtin_bit_cast(f16x2, v[j].w);
                acc0 += wj * (float)v0.x; acc1 += wj * (float)v0.y;
                acc2 += wj * (float)v1.x; acc3 += wj * (float)v1.y;
                acc4 += wj * (float)v2.x; acc5 += wj * (float)v2.y;
                acc6 += wj * (float)v3.x; acc7 += wj * (float)v3.y;
            }
            idxc = idxn;
        }
        float s = spart;
        s += __shfl_xor(s, 1);
        s += __shfl_xor(s, 2);
        s += __shfl_xor(s, 4);
        float inv = 1.f / s;
        uint4 po;
        po.x = packh2(acc0 * inv + ba.x, acc1 * inv + ba.y);
        po.y = packh2(acc2 * inv + ba.z, acc3 * inv + ba.w);
        po.z = packh2(acc4 * inv + bb.x, acc5 * inv + bb.y);
        po.w = packh2(acc6 * inv + bb.z, acc7 * inv + bb.w);
        *(uint4*)(hout + (size_t)node * 64 + g * 4) = po;
    }
}

// ---------------- BatchNorm stats (h in f16) ----------------
__global__ __launch_bounds__(256) void bn_reduce_kernel(const unsigned int* __restrict__ h,
                                                        float* __restrict__ part) {
    int tid = threadIdx.x;
    int cu = tid & 63, half = tid >> 6;
    float s0 = 0.f, q0 = 0.f, s1 = 0.f, q1 = 0.f;
    for (int r = blockIdx.x * 4 + half; r < N_NODES; r += RB * 4) {
        float2 v = unpackh2(h[(size_t)r * 64 + cu]);
        s0 += v.x; q0 += v.x * v.x;
        s1 += v.y; q1 += v.y * v.y;
    }
    __shared__ float sh[256];
    sh[half * 64 + cu] = s0;
    __syncthreads();
    if (tid < 64) {
        float r0 = sh[tid] + sh[64 + tid] + sh[128 + tid] + sh[192 + tid];
        part[blockIdx.x * 256 + tid * 2] = r0;
    }
    __syncthreads();
    sh[half * 64 + cu] = q0;
    __syncthreads();
    if (tid < 64) {
        float r0 = sh[tid] + sh[64 + tid] + sh[128 + tid] + sh[192 + tid];
        part[blockIdx.x * 256 + 128 + tid * 2] = r0;
    }
    __syncthreads();
    sh[half * 64 + cu] = s1;
    __syncthreads();
    if (tid < 64) {
        float r0 = sh[tid] + sh[64 + tid] + sh[128 + tid] + sh[192 + tid];
        part[blockIdx.x * 256 + tid * 2 + 1] = r0;
    }
    __syncthreads();
    sh[half * 64 + cu] = q1;
    __syncthreads();
    if (tid < 64) {
        float r0 = sh[tid] + sh[64 + tid] + sh[128 + tid] + sh[192 + tid];
        part[blockIdx.x * 256 + 128 + tid * 2 + 1] = r0;
    }
}

__global__ void bn_finalize_kernel(const float* __restrict__ part,
                                   const float* __restrict__ gamma,
                                   const float* __restrict__ beta,
                                   float* __restrict__ scale, float* __restrict__ shift) {
    int c = threadIdx.x;  // 128 threads
    float s = 0.f, q = 0.f;
    for (int b = 0; b < RB; b++) {
        s += part[b * 256 + c];
        q += part[b * 256 + 128 + c];
    }
    float m = s / (float)N_NODES;
    float v = q / (float)N_NODES - m * m;
    if (v < 0.f) v = 0.f;
    float rs = rsqrtf(v + EPS);
    float sc = rs * gamma[c];
    scale[c] = sc;
    shift[c] = beta[c] - m * sc;
}

// ---------------- Decode: residual sum on the fly + dot product ----------------
__global__ __launch_bounds__(256) void predict_kernel(const unsigned int* __restrict__ hb,
                                                      const float* __restrict__ scale4,
                                                      const float* __restrict__ shift4,
                                                      const int* __restrict__ eli,
                                                      float* __restrict__ out) {
    int p = blockIdx.x * 4 + (threadIdx.x >> 6);
    if (p >= 8192) return;
    int lane = threadIdx.x & 63;
    int i = eli[p], j = eli[8192 + p];
    int c = lane * 2;
    float ai0 = 0.f, ai1 = 0.f, aj0 = 0.f, aj1 = 0.f;
#pragma unroll
    for (int l = 0; l < N_LAYERS; l++) {
        float sc0 = scale4[l * HID + c], sc1 = scale4[l * HID + c + 1];
        float sh0 = shift4[l * HID + c], sh1 = shift4[l * HID + c + 1];
        float2 vi = unpackh2(hb[(size_t)l * N_NODES * 64 + (size_t)i * 64 + lane]);
        float2 vj = unpackh2(hb[(size_t)l * N_NODES * 64 + (size_t)j * 64 + lane]);
        ai0 += vi.x * sc0 + sh0; ai1 += vi.y * sc1 + sh1;
        aj0 += vj.x * sc0 + sh0; aj1 += vj.y * sc1 + sh1;
    }
    float t = 0.04f * (ai0 * aj0 + ai1 * aj1);  // resw^2 = 0.2^2
#pragma unroll
    for (int off = 32; off; off >>= 1) t += __shfl_xor(t, off, 64);
    if (lane == 0) out[p] = t;
}

extern "C" void kernel_launch(void* const* d_in, const int* in_sizes, int n_in,
                              void* d_out, int out_size, void* d_ws, size_t ws_size,
                              hipStream_t stream) {
    const float* x = (const float*)d_in[0];
    const int* ei = (const int*)d_in[1];
    const int* eli = (const int*)d_in[2];
    const float* Wl = (const float*)d_in[3];
    const float* Wr = (const float*)d_in[4];
    const float* att = (const float*)d_in[5];
    const float* bias = (const float*)d_in[6];
    const float* gamma = (const float*)d_in[7];
    const float* beta = (const float*)d_in[8];
    float* out = (float*)d_out;

    char* ws = (char*)d_ws;
    size_t off = 0;
    unsigned int* hb   = (unsigned int*)(ws + off); off += (size_t)N_LAYERS * N_NODES * HID * 2;  // 4 x f16 h
    unsigned int* xlh  = (unsigned int*)(ws + off); off += (size_t)N_NODES * HID * 2;  // f16
    unsigned int* xrh  = (unsigned int*)(ws + off); off += (size_t)N_NODES * HID * 2;  // f16
    int* rowptr = (int*)(ws + off);   off += ((size_t)(N_NODES + 1) * 4 + 31) & ~31ul;
    unsigned short* csr_src = (unsigned short*)(ws + off); off += ((size_t)(ET + 16) * 2 + 31) & ~31ul;
    int* gcnt  = (int*)(ws + off);    off += (size_t)(NBUCK + 8) * 4;
    int* bcur  = (int*)(ws + off);    off += (size_t)(NBUCK + 8) * 4;
    int* bbase = (int*)(ws + off);    off += (size_t)(NBUCK + 8) * 4;
    int* dhist = (int*)(ws + off);    off += 256 * 4;
    int* dcur  = (int*)(ws + off);    off += 256 * 4;
    int* perm  = (int*)(ws + off);    off += (size_t)N_NODES * 4;
    float* part = (float*)(ws + off); off += (size_t)RB * 256 * 4;
    float* scale4 = (float*)(ws + off); off += (size_t)N_LAYERS * 128 * 4;
    float* shift4 = (float*)(ws + off); off += (size_t)N_LAYERS * 128 * 4;
    unsigned short* wt = (unsigned short*)(ws + off); off += (size_t)8 * HID * HID * 2;
    unsigned int* pairs = (unsigned int*)(ws + off); off += (size_t)ET * 4;  // CSR temp

    // One-time: weights -> bf16 transposed [layer][mat][col][k]
    wconv_kernel<<<8, 256, 0, stream>>>(Wl, Wr, wt);

    // CSR build (dst-sorted), bucketed counting sort; topology fixed across layers
    int nablk = (ET + BCHUNK - 1) / BCHUNK;
    bucket_zero_kernel<<<1, 256, 0, stream>>>(gcnt, dhist);
    bucket_hist_kernel<<<nablk, 256, 0, stream>>>(ei, gcnt);
    bucket_scan_kernel<<<1, 256, 0, stream>>>(gcnt, bbase, bcur, rowptr);
    bucket_scatter_kernel<<<nablk, 256, 0, stream>>>(ei, bcur, pairs);
    bucket_sort_kernel<<<NBUCK, 256, 0, stream>>>(pairs, bbase, rowptr, csr_src);

    // Degree-sorted node permutation (divergence fix for aggregate)
    deg_hist_kernel<<<(N_NODES + 255) / 256, 256, 0, stream>>>(rowptr, dhist);
    deg_scan_kernel<<<1, 256, 0, stream>>>(dhist, dcur);
    deg_scatter_kernel<<<(N_NODES + 255) / 256, 256, 0, stream>>>(rowptr, dcur, perm);

    for (int l = 0; l < N_LAYERS; l++) {
        int donorm = (l == 0) ? 0 : 1;
        const unsigned int* hin_h = (l == 0) ? nullptr : hb + (size_t)(l - 1) * N_NODES * 64;
        gemm_mfma_kernel<<<(N_NODES + 127) / 128, 512, 0, stream>>>(
            (l == 0) ? x : nullptr, hin_h,
            wt + (size_t)l * 2 * HID * HID, xlh, xrh,
            scale4 + (size_t)(l ? l - 1 : 0) * HID, shift4 + (size_t)(l ? l - 1 : 0) * HID,
            donorm);
        aggregate_kernel<<<AGG_BLOCKS, 256, 0, stream>>>(
            xlh, xrh, att + l * HID, bias + l * HID, rowptr, csr_src, perm,
            hb + (size_t)l * N_NODES * 64);
        bn_reduce_kernel<<<RB, 256, 0, stream>>>(hb + (size_t)l * N_NODES * 64, part);
        bn_finalize_kernel<<<1, 128, 0, stream>>>(part, gamma + l * HID, beta + l * HID,
                                                  scale4 + (size_t)l * HID,
                                                  shift4 + (size_t)l * HID);
    }
    predict_kernel<<<8192 / 4, 256, 0, stream>>>(hb, scale4, shift4, eli, out);
}